// Round 1
// baseline (268.503 us; speedup 1.0000x reference)
//
#include <hip/hip_runtime.h>

// NewtonImplicitNet: z0 = x@W_in.T + b_in; 4x implicit blocks (fixed point of
// z = tanh(z@W.T + x), solved by Picard iteration instead of batched Newton —
// same fixed point, contraction factor ~0.4/iter); head GEMM + softmax.
// Fully fused persistent kernel: 256 blocks x 8 rows, W register-resident,
// z/xfix in LDS, 8-way k-split partials reduced through LDS.

#define B_ROWS  2048
#define D_IN    784
#define UNITS   128
#define D_OUT   10
#define RPB     8      // batch rows per block
#define THREADS 256
#define NIT     32     // Picard iterations per implicit block (0.4^32 ~ 1e-13)
#define KPAD    896    // 7 * 128, zero-padded D_IN

__device__ __forceinline__ float rcp_fast(float x) { return __builtin_amdgcn_rcpf(x); }

__device__ __forceinline__ float tanh_fast(float x) {
  // tanh(x) = 1 - 2/(e^{2x}+1); v_exp + v_rcp, ~1e-7 abs error, saturates correctly
  float e = __expf(2.0f * x);
  return 1.0f - 2.0f * rcp_fast(e + 1.0f);
}

__device__ __forceinline__ float4 tanh4(float4 v) {
  return make_float4(tanh_fast(v.x), tanh_fast(v.y), tanh_fast(v.z), tanh_fast(v.w));
}

__device__ __forceinline__ float4 f4fma(float a, const float4 b, float4 c) {
  c.x = fmaf(a, b.x, c.x);
  c.y = fmaf(a, b.y, c.y);
  c.z = fmaf(a, b.z, c.z);
  c.w = fmaf(a, b.w, c.w);
  return c;
}
__device__ __forceinline__ float4 f4add(float4 a, float4 b) {
  return make_float4(a.x + b.x, a.y + b.y, a.z + b.z, a.w + b.w);
}

union SmemU {
  float xb[RPB][KPAD];        // phase 0 only: staged x rows (28 KB)
  float P[8][RPB][UNITS];     // k-group partial sums (32 KB)
};

__global__ __launch_bounds__(THREADS) void fused_net(
    const float* __restrict__ x,
    const float* __restrict__ W_in,
    const float* __restrict__ b_in,
    const float* __restrict__ W1,
    const float* __restrict__ W2,
    const float* __restrict__ W3,
    const float* __restrict__ W4,
    const float* __restrict__ W_out,
    const float* __restrict__ b_out,
    float* __restrict__ out)
{
  __shared__ __align__(16) SmemU sh;
  __shared__ __align__(16) float zbuf[RPB][UNITS];   // current Picard iterate
  __shared__ __align__(16) float xfix[RPB][UNITS];   // block input (the "x" of the fixed point)
  __shared__ float lg[RPB][D_OUT];

  const int t  = threadIdx.x;
  const int ug = t & 31;          // unit group: covers u4..u4+3
  const int kg = t >> 5;          // k group: covers k0..k0+15  (also doubles as row id in reduce)
  const int u4 = ug * 4;
  const int k0 = kg * 16;
  const int r0 = blockIdx.x * RPB;

  // ---------------- stage x rows into LDS (zero-padded to KPAD) ----------------
  for (int idx = t; idx < RPB * (KPAD / 4); idx += THREADS) {
    int row = idx / (KPAD / 4);
    int c4  = idx % (KPAD / 4);
    int k   = c4 * 4;
    float4 v = make_float4(0.f, 0.f, 0.f, 0.f);
    const float* xr = x + (size_t)(r0 + row) * D_IN;
    if (k + 3 < D_IN) {
      v = *(const float4*)(xr + k);
    } else if (k < D_IN) {
      v.x = xr[k];
      if (k + 1 < D_IN) v.y = xr[k + 1];
      if (k + 2 < D_IN) v.z = xr[k + 2];
    }
    *(float4*)&sh.xb[row][k] = v;
  }
  __syncthreads();

  float4 p[RPB];
  float4 wreg[16];   // wreg[k'][j] = W[u4+j][k0+k'] — iteration-invariant slice

#pragma unroll
  for (int r = 0; r < RPB; ++r) p[r] = make_float4(0.f, 0.f, 0.f, 0.f);

  // ---------------- input GEMM: p += x @ W_in.T over 7 k-chunks of 128 ----------------
  for (int ch = 0; ch < 7; ++ch) {
    const int kbase = ch * 128 + k0;
#pragma unroll
    for (int m = 0; m < 4; ++m) {
      const int k = kbase + 4 * m;
      float aj[4][4];
#pragma unroll
      for (int j = 0; j < 4; ++j) {
        const float* wr = W_in + (size_t)(u4 + j) * D_IN;
        float4 v = make_float4(0.f, 0.f, 0.f, 0.f);
        if (k + 3 < D_IN) {
          v = *(const float4*)(wr + k);
        } else {
          if (k     < D_IN) v.x = wr[k];
          if (k + 1 < D_IN) v.y = wr[k + 1];
          if (k + 2 < D_IN) v.z = wr[k + 2];
          if (k + 3 < D_IN) v.w = wr[k + 3];
        }
        aj[j][0] = v.x; aj[j][1] = v.y; aj[j][2] = v.z; aj[j][3] = v.w;
      }
#pragma unroll
      for (int i = 0; i < 4; ++i)
        wreg[4 * m + i] = make_float4(aj[0][i], aj[1][i], aj[2][i], aj[3][i]);
    }
#pragma unroll
    for (int r = 0; r < RPB; ++r) {
#pragma unroll
      for (int m = 0; m < 4; ++m) {
        float4 zq = *(const float4*)&sh.xb[r][kbase + 4 * m];
        p[r] = f4fma(zq.x, wreg[4 * m + 0], p[r]);
        p[r] = f4fma(zq.y, wreg[4 * m + 1], p[r]);
        p[r] = f4fma(zq.z, wreg[4 * m + 2], p[r]);
        p[r] = f4fma(zq.w, wreg[4 * m + 3], p[r]);
      }
    }
  }

  __syncthreads();   // all xb reads done; union region becomes P
#pragma unroll
  for (int r = 0; r < RPB; ++r)
    *(float4*)&sh.P[kg][r][u4] = p[r];
  __syncthreads();

  {
    float4 s = *(const float4*)&b_in[u4];
#pragma unroll
    for (int g = 0; g < 8; ++g)
      s = f4add(s, *(const float4*)&sh.P[g][kg][u4]);
    *(float4*)&xfix[kg][u4] = s;            // block-1 input
    *(float4*)&zbuf[kg][u4] = tanh4(s);     // z0 = tanh(x), same start as reference
  }
  __syncthreads();

  // ---------------- 4 implicit blocks ----------------
  const float* const Ws[4] = {W1, W2, W3, W4};

  for (int wb = 0; wb < 4; ++wb) {
    const float* __restrict__ W = Ws[wb];
    // load register-resident transposed W slice: wreg[k'][j] = W[u4+j][k0+k']
#pragma unroll
    for (int m = 0; m < 4; ++m) {
      float aj[4][4];
#pragma unroll
      for (int j = 0; j < 4; ++j) {
        float4 v = *(const float4*)(W + (size_t)(u4 + j) * UNITS + k0 + 4 * m);
        aj[j][0] = v.x; aj[j][1] = v.y; aj[j][2] = v.z; aj[j][3] = v.w;
      }
#pragma unroll
      for (int i = 0; i < 4; ++i)
        wreg[4 * m + i] = make_float4(aj[0][i], aj[1][i], aj[2][i], aj[3][i]);
    }

    for (int it = 0; it < NIT; ++it) {
      // partials: p[r] = sum over this thread's 16 k of z[r][k] * W[u4..u4+3][k]
#pragma unroll
      for (int r = 0; r < RPB; ++r) {
        float4 acc = make_float4(0.f, 0.f, 0.f, 0.f);
#pragma unroll
        for (int m = 0; m < 4; ++m) {
          float4 zq = *(const float4*)&zbuf[r][k0 + 4 * m];   // broadcast read
          acc = f4fma(zq.x, wreg[4 * m + 0], acc);
          acc = f4fma(zq.y, wreg[4 * m + 1], acc);
          acc = f4fma(zq.z, wreg[4 * m + 2], acc);
          acc = f4fma(zq.w, wreg[4 * m + 3], acc);
        }
        p[r] = acc;
      }
#pragma unroll
      for (int r = 0; r < RPB; ++r)
        *(float4*)&sh.P[kg][r][u4] = p[r];
      __syncthreads();

      // reduce 8 k-groups, add xfix, tanh, write back (thread owns row kg, cols u4..u4+3)
      float4 s = *(const float4*)&xfix[kg][u4];
#pragma unroll
      for (int g = 0; g < 8; ++g)
        s = f4add(s, *(const float4*)&sh.P[g][kg][u4]);
      *(float4*)&zbuf[kg][u4] = tanh4(s);
      __syncthreads();
    }

    if (wb < 3) {
      // next block's input is this block's output; z restarts at tanh(input)
      float4 zo = *(const float4*)&zbuf[kg][u4];
      *(float4*)&xfix[kg][u4] = zo;
      *(float4*)&zbuf[kg][u4] = tanh4(zo);
      __syncthreads();
    }
  }

  // ---------------- head: logits + softmax ----------------
  if (t < RPB * D_OUT) {
    int r = t / D_OUT, c = t % D_OUT;
    float s = b_out[c];
    const float* wo = W_out + (size_t)c * UNITS;
#pragma unroll
    for (int u = 0; u < UNITS; u += 4) {
      float4 zq = *(const float4*)&zbuf[r][u];
      float4 wq = *(const float4*)(wo + u);
      s = fmaf(zq.x, wq.x, s);
      s = fmaf(zq.y, wq.y, s);
      s = fmaf(zq.z, wq.z, s);
      s = fmaf(zq.w, wq.w, s);
    }
    lg[r][c] = s;
  }
  __syncthreads();
  if (t < RPB) {
    float m = lg[t][0];
#pragma unroll
    for (int c = 1; c < D_OUT; ++c) m = fmaxf(m, lg[t][c]);
    float e[D_OUT];
    float sum = 0.f;
#pragma unroll
    for (int c = 0; c < D_OUT; ++c) {
      e[c] = __expf(lg[t][c] - m);
      sum += e[c];
    }
    float rs = rcp_fast(sum);
    float* orow = out + (size_t)(r0 + t) * D_OUT;
#pragma unroll
    for (int c = 0; c < D_OUT; ++c) orow[c] = e[c] * rs;
  }
}

extern "C" void kernel_launch(void* const* d_in, const int* in_sizes, int n_in,
                              void* d_out, int out_size, void* d_ws, size_t ws_size,
                              hipStream_t stream) {
  const float* x     = (const float*)d_in[0];
  const float* W_in  = (const float*)d_in[1];
  const float* b_in  = (const float*)d_in[2];
  const float* W1    = (const float*)d_in[3];
  const float* W2    = (const float*)d_in[4];
  const float* W3    = (const float*)d_in[5];
  const float* W4    = (const float*)d_in[6];
  const float* W_out = (const float*)d_in[7];
  const float* b_out = (const float*)d_in[8];
  float* outp = (float*)d_out;

  dim3 grid(B_ROWS / RPB);
  dim3 block(THREADS);
  hipLaunchKernelGGL(fused_net, grid, block, 0, stream,
                     x, W_in, b_in, W1, W2, W3, W4, W_out, b_out, outp);
}